// Round 7
// baseline (32.605 us; speedup 1.0000x reference)
//
#include <hip/hip_runtime.h>

// out[tok, d] = W[x[tok], d] + 2.0f * sum_r lora_B[d, r] * lora_A[r, x[tok]]
// x (16384,) i32, W (V=50257, 1024) f32, lora_A (8, V) f32, lora_B (1024, 8) f32,
// out (16384, 1024) f32.
//
// Two-kernel plan:
//   K0: At[v][r] = 2 * lora_A[r][v]   (V x 8 f32 in d_ws, 1.6 MB — L2-resident)
//   K1: main gather+LoRA, a-vector fetched as two broadcast dwordx4 from At.

#define LORA_D 1024
#define LORA_R 8
#define BLOCK  256
#define TOKS_PER_BLOCK 8

typedef float v4f __attribute__((ext_vector_type(4)));

__global__ void transpose_a_kernel(const float* __restrict__ lora_A,
                                   float* __restrict__ At, int V)
{
    const int v = blockIdx.x * blockDim.x + threadIdx.x;
    if (v < V) {
        #pragma unroll
        for (int r = 0; r < LORA_R; ++r)
            At[(size_t)v * LORA_R + r] = 2.0f * lora_A[(size_t)r * V + v];
    }
}

__global__ __launch_bounds__(BLOCK, 4) void lora_embed_kernel(
    const int*   __restrict__ x,
    const float* __restrict__ W,
    const float* __restrict__ At,      // (V, 8), pre-scaled by 2
    const float* __restrict__ lora_B,
    float*       __restrict__ out,
    int n_tokens, int V)
{
    const int tid = threadIdx.x;
    const int d0  = tid * 4;          // this thread's 4 output dims

    // Stage this thread's 4x8 slice of lora_B into registers (unscaled;
    // the 2.0 factor is folded into At).
    float b[4][LORA_R];
    #pragma unroll
    for (int j = 0; j < 4; ++j) {
        const v4f lo = *reinterpret_cast<const v4f*>(&lora_B[(size_t)(d0 + j) * LORA_R + 0]);
        const v4f hi = *reinterpret_cast<const v4f*>(&lora_B[(size_t)(d0 + j) * LORA_R + 4]);
        b[j][0] = lo.x; b[j][1] = lo.y; b[j][2] = lo.z; b[j][3] = lo.w;
        b[j][4] = hi.x; b[j][5] = hi.y; b[j][6] = hi.z; b[j][7] = hi.w;
    }

    const int tok0 = blockIdx.x * TOKS_PER_BLOCK;

    if (tok0 + TOKS_PER_BLOCK <= n_tokens) {
        int t[TOKS_PER_BLOCK];
        #pragma unroll
        for (int k = 0; k < TOKS_PER_BLOCK; ++k)
            t[k] = x[tok0 + k];                       // uniform -> scalar loads

        // Issue all 8 W-row gathers before any consumption.
        v4f w[TOKS_PER_BLOCK];
        #pragma unroll
        for (int k = 0; k < TOKS_PER_BLOCK; ++k)
            w[k] = *reinterpret_cast<const v4f*>(&W[(size_t)t[k] * LORA_D + d0]);

        #pragma unroll
        for (int k = 0; k < TOKS_PER_BLOCK; ++k) {
            // All 8 a-values in two broadcast 16B loads (was 8 scattered loads).
            const v4f a0 = *reinterpret_cast<const v4f*>(&At[(size_t)t[k] * LORA_R + 0]);
            const v4f a1 = *reinterpret_cast<const v4f*>(&At[(size_t)t[k] * LORA_R + 4]);
            const float a[LORA_R] = {a0.x, a0.y, a0.z, a0.w, a1.x, a1.y, a1.z, a1.w};

            float acc[4] = {w[k].x, w[k].y, w[k].z, w[k].w};
            #pragma unroll
            for (int j = 0; j < 4; ++j)
                #pragma unroll
                for (int r = 0; r < LORA_R; ++r)
                    acc[j] = fmaf(b[j][r], a[r], acc[j]);

            // NT store: out is write-once streaming.
            v4f o; o.x = acc[0]; o.y = acc[1]; o.z = acc[2]; o.w = acc[3];
            __builtin_nontemporal_store(
                o, reinterpret_cast<v4f*>(&out[(size_t)(tok0 + k) * LORA_D + d0]));
        }
    } else {
        // Tail path (not hit for 16384 tokens, kept for safety).
        for (int tok = tok0; tok < n_tokens; ++tok) {
            const int t = x[tok];
            const v4f a0 = *reinterpret_cast<const v4f*>(&At[(size_t)t * LORA_R + 0]);
            const v4f a1 = *reinterpret_cast<const v4f*>(&At[(size_t)t * LORA_R + 4]);
            const float a[LORA_R] = {a0.x, a0.y, a0.z, a0.w, a1.x, a1.y, a1.z, a1.w};
            const v4f w = *reinterpret_cast<const v4f*>(&W[(size_t)t * LORA_D + d0]);
            float acc[4] = {w.x, w.y, w.z, w.w};
            #pragma unroll
            for (int j = 0; j < 4; ++j)
                #pragma unroll
                for (int r = 0; r < LORA_R; ++r)
                    acc[j] = fmaf(b[j][r], a[r], acc[j]);
            v4f o; o.x = acc[0]; o.y = acc[1]; o.z = acc[2]; o.w = acc[3];
            *reinterpret_cast<v4f*>(&out[(size_t)tok * LORA_D + d0]) = o;
        }
    }
}

extern "C" void kernel_launch(void* const* d_in, const int* in_sizes, int n_in,
                              void* d_out, int out_size, void* d_ws, size_t ws_size,
                              hipStream_t stream) {
    const int*   x      = (const int*)  d_in[0];
    const float* W      = (const float*)d_in[1];
    const float* lora_A = (const float*)d_in[2];
    const float* lora_B = (const float*)d_in[3];
    float*       out    = (float*)d_out;
    float*       At     = (float*)d_ws;          // V*8 f32 = 1.6 MB scratch

    const int n_tokens = in_sizes[0];            // B*S = 16384
    const int V        = in_sizes[1] / LORA_D;   // 50257

    const int tgrid = (V + BLOCK - 1) / BLOCK;   // 197 blocks
    transpose_a_kernel<<<tgrid, BLOCK, 0, stream>>>(lora_A, At, V);

    const int grid = (n_tokens + TOKS_PER_BLOCK - 1) / TOKS_PER_BLOCK;  // 2048
    lora_embed_kernel<<<grid, BLOCK, 0, stream>>>(x, W, At, lora_B, out,
                                                  n_tokens, V);
}

// Round 8
// 28.420 us; speedup vs baseline: 1.1472x; 1.1472x over previous
//
#include <hip/hip_runtime.h>

// out[tok, d] = W[x[tok], d] + 2.0f * sum_r lora_B[d, r] * lora_A[r, x[tok]]
// x (16384,) i32, W (V=50257, 1024) f32, lora_A (8, V) f32, lora_B (1024, 8) f32,
// out (16384, 1024) f32.
//
// Final config (best measured, R5 = 28.5 us):
//  - 2048 blocks x 256 threads, 8 tokens/block, one float4 of the row per thread
//  - all 8 W-row gathers issued before consumption (plain cached loads;
//    NT loads regressed — W benefits from L2/L3 residency)
//  - lora_A fetched as 8 wave-uniform broadcast loads (cache-resident;
//    pre-transposing into ws regressed: extra kernel cost > VMEM savings)
//  - nontemporal stores for the write-once output stream (+3%)
//  - launch_bounds(256,4): no spill, 16 waves/CU

#define LORA_D 1024
#define LORA_R 8
#define BLOCK  256
#define TOKS_PER_BLOCK 8

typedef float v4f __attribute__((ext_vector_type(4)));

__global__ __launch_bounds__(BLOCK, 4) void lora_embed_kernel(
    const int*   __restrict__ x,
    const float* __restrict__ W,
    const float* __restrict__ lora_A,
    const float* __restrict__ lora_B,
    float*       __restrict__ out,
    int n_tokens, int V)
{
    const int tid = threadIdx.x;
    const int d0  = tid * 4;          // this thread's 4 output dims

    // Stage this thread's 4x8 slice of lora_B into registers (scaled by 2).
    float b[4][LORA_R];
    #pragma unroll
    for (int j = 0; j < 4; ++j) {
        const v4f lo = *reinterpret_cast<const v4f*>(&lora_B[(size_t)(d0 + j) * LORA_R + 0]);
        const v4f hi = *reinterpret_cast<const v4f*>(&lora_B[(size_t)(d0 + j) * LORA_R + 4]);
        b[j][0] = 2.0f * lo.x; b[j][1] = 2.0f * lo.y;
        b[j][2] = 2.0f * lo.z; b[j][3] = 2.0f * lo.w;
        b[j][4] = 2.0f * hi.x; b[j][5] = 2.0f * hi.y;
        b[j][6] = 2.0f * hi.z; b[j][7] = 2.0f * hi.w;
    }

    const int tok0 = blockIdx.x * TOKS_PER_BLOCK;

    if (tok0 + TOKS_PER_BLOCK <= n_tokens) {
        int t[TOKS_PER_BLOCK];
        #pragma unroll
        for (int k = 0; k < TOKS_PER_BLOCK; ++k)
            t[k] = x[tok0 + k];                       // uniform -> scalar loads

        // Issue all 8 W-row gathers before any consumption.
        v4f w[TOKS_PER_BLOCK];
        #pragma unroll
        for (int k = 0; k < TOKS_PER_BLOCK; ++k)
            w[k] = *reinterpret_cast<const v4f*>(&W[(size_t)t[k] * LORA_D + d0]);

        #pragma unroll
        for (int k = 0; k < TOKS_PER_BLOCK; ++k) {
            float a[LORA_R];
            #pragma unroll
            for (int r = 0; r < LORA_R; ++r)          // uniform, cache-resident
                a[r] = lora_A[(size_t)r * V + t[k]];

            float acc[4] = {w[k].x, w[k].y, w[k].z, w[k].w};
            #pragma unroll
            for (int j = 0; j < 4; ++j)
                #pragma unroll
                for (int r = 0; r < LORA_R; ++r)
                    acc[j] = fmaf(b[j][r], a[r], acc[j]);

            // NT store: out is write-once streaming.
            v4f o; o.x = acc[0]; o.y = acc[1]; o.z = acc[2]; o.w = acc[3];
            __builtin_nontemporal_store(
                o, reinterpret_cast<v4f*>(&out[(size_t)(tok0 + k) * LORA_D + d0]));
        }
    } else {
        // Tail path (not hit for 16384 tokens, kept for safety).
        for (int tok = tok0; tok < n_tokens; ++tok) {
            const int t = x[tok];
            float a[LORA_R];
            #pragma unroll
            for (int r = 0; r < LORA_R; ++r)
                a[r] = lora_A[(size_t)r * V + t];
            const v4f w = *reinterpret_cast<const v4f*>(&W[(size_t)t * LORA_D + d0]);
            float acc[4] = {w.x, w.y, w.z, w.w};
            #pragma unroll
            for (int j = 0; j < 4; ++j)
                #pragma unroll
                for (int r = 0; r < LORA_R; ++r)
                    acc[j] = fmaf(b[j][r], a[r], acc[j]);
            v4f o; o.x = acc[0]; o.y = acc[1]; o.z = acc[2]; o.w = acc[3];
            *reinterpret_cast<v4f*>(&out[(size_t)tok * LORA_D + d0]) = o;
        }
    }
}

extern "C" void kernel_launch(void* const* d_in, const int* in_sizes, int n_in,
                              void* d_out, int out_size, void* d_ws, size_t ws_size,
                              hipStream_t stream) {
    const int*   x      = (const int*)  d_in[0];
    const float* W      = (const float*)d_in[1];
    const float* lora_A = (const float*)d_in[2];
    const float* lora_B = (const float*)d_in[3];
    float*       out    = (float*)d_out;

    const int n_tokens = in_sizes[0];            // B*S = 16384
    const int V        = in_sizes[1] / LORA_D;   // 50257

    const int grid = (n_tokens + TOKS_PER_BLOCK - 1) / TOKS_PER_BLOCK;  // 2048
    lora_embed_kernel<<<grid, BLOCK, 0, stream>>>(x, W, lora_A, lora_B, out,
                                                  n_tokens, V);
}